// Round 9
// baseline (342.620 us; speedup 1.0000x reference)
//
#include <hip/hip_runtime.h>
#include <cstdint>

#define B_SZ 8192
#define IN_SZ 1024
#define H_SZ 1024

typedef unsigned short u16;
typedef __bf16 bf16_t;
typedef bf16_t bf16x8 __attribute__((ext_vector_type(8)));
typedef float floatx4 __attribute__((ext_vector_type(4)));

__device__ __forceinline__ u16 f2bf(float f) {
    unsigned int u = __float_as_uint(f);
    u += 0x7fffu + ((u >> 16) & 1u);   // RNE
    return (u16)(u >> 16);
}

__device__ __forceinline__ ushort4 cvt4(float4 v) {
    ushort4 o;
    o.x = f2bf(v.x); o.y = f2bf(v.y); o.z = f2bf(v.z); o.w = f2bf(v.w);
    return o;
}

// async global->LDS, 16B per lane; LDS dest = wave-uniform base + lane*16
__device__ __forceinline__ void g2l16(const u16* g, u16* l) {
    __builtin_amdgcn_global_load_lds(
        (__attribute__((address_space(1))) void*)(uintptr_t)g,
        (__attribute__((address_space(3))) void*)(uint32_t)(uintptr_t)l,
        16, 0, 0);
}

// phase boundary: pin order, counted vmcnt (NEVER 0 in steady state), raw barrier
template <int N>
__device__ __forceinline__ void phase_end() {
    __builtin_amdgcn_sched_barrier(0);
    if constexpr (N == 0) asm volatile("s_waitcnt vmcnt(0)" ::: "memory");
    else if constexpr (N == 4) asm volatile("s_waitcnt vmcnt(4)" ::: "memory");
    else if constexpr (N == 8) asm volatile("s_waitcnt vmcnt(8)" ::: "memory");
    __builtin_amdgcn_s_barrier();
    __builtin_amdgcn_sched_barrier(0);
}

// ---------------- fused fp32 -> bf16 conversion into K-concat layouts -----------
// Acat[8192][2048] = [bf16(input) | bf16(hidden)]
// Brz [2048][2048] = [[Wir|Whr],[Wiz|Whz]];  Bh [1024][2048] = [Wih|Whh]
__global__ __launch_bounds__(256) void cvt_all(
    const float* __restrict__ x, const float* __restrict__ h,
    const float* __restrict__ Wir, const float* __restrict__ Whr,
    const float* __restrict__ Wiz, const float* __restrict__ Whz,
    const float* __restrict__ Wih, const float* __restrict__ Whh,
    u16* __restrict__ Acat, u16* __restrict__ Brz, u16* __restrict__ Bh) {
    const int b = blockIdx.x;
    const int t = threadIdx.x;
    if (b < 8192) {
        float4 v = ((const float4*)(x + (size_t)b * 1024))[t];
        ((ushort4*)(Acat + (size_t)b * 2048))[t] = cvt4(v);
    } else if (b < 16384) {
        const int m = b - 8192;
        float4 v = ((const float4*)(h + (size_t)m * 1024))[t];
        ((ushort4*)(Acat + (size_t)m * 2048 + 1024))[t] = cvt4(v);
    } else {
        const int wb = b - 16384;   // 0..6143
        const int w = wb >> 10;
        const int n = wb & 1023;
        const float* src;
        u16* dst;
        switch (w) {
            case 0: src = Wir; dst = Brz + (size_t)n * 2048;               break;
            case 1: src = Whr; dst = Brz + (size_t)n * 2048 + 1024;        break;
            case 2: src = Wiz; dst = Brz + (size_t)(n + 1024) * 2048;      break;
            case 3: src = Whz; dst = Brz + (size_t)(n + 1024) * 2048 + 1024; break;
            case 4: src = Wih; dst = Bh + (size_t)n * 2048;                break;
            default: src = Whh; dst = Bh + (size_t)n * 2048 + 1024;        break;
        }
        float4 v = ((const float4*)(src + (size_t)n * 1024))[t];
        ((ushort4*)dst)[t] = cvt4(v);
    }
}

// ---------------- K=2048 NT GEMM, 128x128 ring-3 + counted vmcnt + T2 swizzle ---
// EXACT r6 body (refcheck-passed) with ONE change at the launch level:
// __launch_bounds__(256, 3) on the wrappers forces a 170-reg budget -> 3 waves/
// SIMD -> 3 co-resident blocks/CU (LDS 48KB fits 3). Session model: effective
// VMEM-staging cost/instr drops monotonically with blocks/CU (130 @1, ~80 @1.5-2,
// ~31 @3 per m97) -- cross-block TLP fills the phase-boundary stalls that
// intra-block scheduling (r5/r7/r8 structural variants, all ~110-147us) cannot.
// NOTE: (256,4) is the r1 disaster (128-reg strangulation); (256,3) leaves slack
// (r6 measured 92 VGPR + 64 acc = 156 <= 170).
// MODE 0 (r+z, N=2048): col<1024 -> out_rh=bf16(sigmoid(C+b)*hidden);
//                       col>=1024 -> out_zf[.,c-1024]=sigmoid(C+b)
// MODE 2 (h~, N=1024): ht=tanh(C+b); out_f = z*hidden + (1-z)*ht
template <int MODE, int LNBN>
__device__ __forceinline__ void gemm_core(
    const u16* __restrict__ A0, const u16* __restrict__ A1,
    const int sA0, const int sA1,
    const u16* __restrict__ Bw,
    const float* __restrict__ bx0, const float* __restrict__ bh0,
    const float* __restrict__ bx1, const float* __restrict__ bh1,
    const float* __restrict__ hidden, const float* __restrict__ zbuf,
    u16* __restrict__ out_rh, float* __restrict__ out_zf,
    float* __restrict__ out_f) {
    constexpr int BM = 128, BN = 128, BK = 32, NKT = 64;   // K = 2048
    constexpr int FM = 4, FN = 4;          // per-wave 64x64, 16 MFMA/tile
    constexpr int LS = 4;                  // loads/thread/tile (AG=2 + BG=2)

    __shared__ u16 As[3][BM * BK];         // 3 x 8 KB
    __shared__ u16 Bs[3][BN * BK];         // 3 x 8 KB

    const int tid = threadIdx.x;
    const int wave = tid >> 6;
    const int lane = tid & 63;
    // chunked XCD swizzle (nwg % 8 == 0: 1024 / 512)
    const int nwg = gridDim.x;
    const int wid = blockIdx.x;
    const int swz = (wid & 7) * (nwg >> 3) + (wid >> 3);
    const int bn = swz & ((1 << LNBN) - 1);
    const int bm = swz >> LNBN;
    const int wr = wave >> 1, wc = wave & 1;   // 2x2 wave grid

    const floatx4 z4 = {0.f, 0.f, 0.f, 0.f};
    floatx4 acc[FM][FN];
#pragma unroll
    for (int i = 0; i < FM; ++i)
#pragma unroll
        for (int j = 0; j < FN; ++j) acc[i][j] = z4;

    // staging source coords (inverse swizzle on global address); A and B tiles are
    // both 512 chunks over 256 threads -> same row/k tables
    int row[2], gk[2];
#pragma unroll
    for (int j = 0; j < 2; ++j) {
        const int c = j * 256 + tid;       // chunk 0..511
        const int sup = c >> 3;
        const int u = (c & 7) ^ (sup & 7);
        row[j] = sup * 2 + (u >> 2);
        gk[j] = (u & 3) * 8;
    }

    // swizzled ds_read bases (u16 idx): frag i at base + i*512
    const int mr = lane & 15;
    const int sg = lane >> 4;              // k-slot 0..3
    const int R0 = wr * 64 + mr;
    const int baseA = (R0 >> 1) * 64 + (((((R0 & 1) << 2) | sg) ^ ((R0 >> 1) & 7)) << 3);
    const int C0 = wc * 64 + mr;
    const int baseB = (C0 >> 1) * 64 + (((((C0 & 1) << 2) | sg) ^ ((C0 >> 1) & 7)) << 3);

    auto stage = [&](int buf, int t) {
        const bool seg = t >= NKT / 2;
        const u16* __restrict__ Ab = seg ? A1 : A0;
        const int sA = seg ? sA1 : sA0;
        const int ka = (t & (NKT / 2 - 1)) * BK;
        const int kb = t * BK;
        u16* Asb = &As[buf][0];
        u16* Bsb = &Bs[buf][0];
#pragma unroll
        for (int j = 0; j < 2; ++j)
            g2l16(Ab + (size_t)(bm * BM + row[j]) * sA + ka + gk[j],
                  Asb + (j * 256 + wave * 64) * 8);
#pragma unroll
        for (int j = 0; j < 2; ++j)
            g2l16(Bw + (size_t)(bn * BN + row[j]) * 2048 + kb + gk[j],
                  Bsb + (j * 256 + wave * 64) * 8);
    };

    auto compute = [&](int buf) {
        const u16* Asb = &As[buf][0];
        const u16* Bsb = &Bs[buf][0];
        bf16x8 af[FM], bv[FN];
#pragma unroll
        for (int i = 0; i < FM; ++i)
            af[i] = *(const bf16x8*)&Asb[baseA + i * 512];
#pragma unroll
        for (int j = 0; j < FN; ++j)
            bv[j] = *(const bf16x8*)&Bsb[baseB + j * 512];
        __builtin_amdgcn_s_setprio(1);
#pragma unroll
        for (int i = 0; i < FM; ++i)
#pragma unroll
            for (int j = 0; j < FN; ++j)
                acc[i][j] = __builtin_amdgcn_mfma_f32_16x16x32_bf16(
                    af[i], bv[j], acc[i][j], 0, 0, 0);
        __builtin_amdgcn_s_setprio(0);
    };

    auto step = [&](int t, int bS, int bC) {
        stage(bS, t + 2);   // next+1 tile's loads fly under this tile's compute
        compute(bC);
        phase_end<LS>();    // tile t+1 resident; t+2 in flight (in-order completion)
    };

    // prologue: 2 tiles in flight
    stage(0, 0); stage(1, 1);
    phase_end<LS>();                       // tile 0 resident
    for (int t = 0; t < 60; t += 3) {      // buffers (t+2)%3 / t%3, compile-time
        step(t, 2, 0); step(t + 1, 0, 1); step(t + 2, 1, 2);
    }
    step(60, 2, 0); step(61, 0, 1);
    compute(2);                            // tile 62
    phase_end<0>();                        // drain tile 63
    compute(0);                            // tile 63

    // epilogue: C/D layout col=lane&15, row=(lane>>4)*4+reg (m89/m91 verified)
    const int colBase = bn * BN + wc * 64 + (lane & 15);
    const int rowBase = bm * BM + wr * 64 + (lane >> 4) * 4;
    if constexpr (MODE == 0) {
        const bool is_r = (colBase < H_SZ);   // block-uniform (1024 % 128 == 0)
#pragma unroll
        for (int j = 0; j < FN; ++j) {
            const int coln = colBase + j * 16;
            const int cb = is_r ? coln : coln - H_SZ;
            const float bias = is_r ? (bx0[cb] + bh0[cb]) : (bx1[cb] + bh1[cb]);
#pragma unroll
            for (int i = 0; i < FM; ++i) {
#pragma unroll
                for (int r = 0; r < 4; ++r) {
                    const int rown = rowBase + i * 16 + r;
                    const size_t idx = (size_t)rown * H_SZ + cb;
                    const float v = acc[i][j][r] + bias;
                    const float sg2 = 1.0f / (1.0f + __expf(-v));
                    if (is_r) {
                        out_rh[idx] = f2bf(sg2 * hidden[idx]);
                    } else {
                        out_zf[idx] = sg2;
                    }
                }
            }
        }
    } else {
#pragma unroll
        for (int j = 0; j < FN; ++j) {
            const int coln = colBase + j * 16;
            const float bias = bx0[coln] + bh0[coln];
#pragma unroll
            for (int i = 0; i < FM; ++i) {
#pragma unroll
                for (int r = 0; r < 4; ++r) {
                    const int rown = rowBase + i * 16 + r;
                    const size_t idx = (size_t)rown * H_SZ + coln;
                    const float v = acc[i][j][r] + bias;
                    const float ht = tanhf(v);
                    const float zz = zbuf[idx];
                    const float hh = hidden[idx];
                    out_f[idx] = zz * hh + (1.0f - zz) * ht;
                }
            }
        }
    }
}

// distinct names for rocprof; (256,3) = the occupancy-floor experiment
__global__ __launch_bounds__(256, 3) void gemm_rz(
    const u16* __restrict__ A0, const u16* __restrict__ A1,
    const u16* __restrict__ Bw,
    const float* __restrict__ bx0, const float* __restrict__ bh0,
    const float* __restrict__ bx1, const float* __restrict__ bh1,
    const float* __restrict__ hidden,
    u16* __restrict__ out_rh, float* __restrict__ out_zf) {
    gemm_core<0, 4>(A0, A1, 2048, 2048, Bw, bx0, bh0, bx1, bh1,
                    hidden, nullptr, out_rh, out_zf, nullptr);
}

__global__ __launch_bounds__(256, 3) void gemm_h(
    const u16* __restrict__ A0, const u16* __restrict__ A1,
    const u16* __restrict__ Bw,
    const float* __restrict__ bx0, const float* __restrict__ bh0,
    const float* __restrict__ hidden, const float* __restrict__ zbuf,
    float* __restrict__ out_f) {
    gemm_core<2, 3>(A0, A1, 2048, 1024, Bw, bx0, bh0, nullptr, nullptr,
                    hidden, zbuf, nullptr, nullptr, out_f);
}

// ---------------- row-wise log_softmax over H=1024 ----------------
__global__ __launch_bounds__(256) void lsm_kernel(const float* __restrict__ nh,
                                                  float* __restrict__ out) {
    const int row = blockIdx.x;
    const int tid = threadIdx.x;
    const int wave = tid >> 6, lane = tid & 63;
    const float4 v = ((const float4*)(nh + (size_t)row * H_SZ))[tid];
    __shared__ float redm[4];
    __shared__ float reds[4];
    float m = fmaxf(fmaxf(v.x, v.y), fmaxf(v.z, v.w));
#pragma unroll
    for (int o = 32; o; o >>= 1) m = fmaxf(m, __shfl_xor(m, o));
    if (lane == 0) redm[wave] = m;
    __syncthreads();
    const float M = fmaxf(fmaxf(redm[0], redm[1]), fmaxf(redm[2], redm[3]));
    float s = __expf(v.x - M) + __expf(v.y - M) + __expf(v.z - M) + __expf(v.w - M);
#pragma unroll
    for (int o = 32; o; o >>= 1) s += __shfl_xor(s, o);
    if (lane == 0) reds[wave] = s;
    __syncthreads();
    const float S = reds[0] + reds[1] + reds[2] + reds[3];
    const float lse = M + __logf(S);
    float4 ov;
    ov.x = v.x - lse; ov.y = v.y - lse; ov.z = v.z - lse; ov.w = v.w - lse;
    ((float4*)(out + (size_t)row * H_SZ))[tid] = ov;
}

extern "C" void kernel_launch(void* const* d_in, const int* in_sizes, int n_in,
                              void* d_out, int out_size, void* d_ws, size_t ws_size,
                              hipStream_t stream) {
    const float* input  = (const float*)d_in[0];
    const float* hidden = (const float*)d_in[1];
    const float* Wir = (const float*)d_in[2];  const float* bir = (const float*)d_in[3];
    const float* Whr = (const float*)d_in[4];  const float* bhr = (const float*)d_in[5];
    const float* Wiz = (const float*)d_in[6];  const float* biz = (const float*)d_in[7];
    const float* Whz = (const float*)d_in[8];  const float* bhz = (const float*)d_in[9];
    const float* Wih = (const float*)d_in[10]; const float* bih = (const float*)d_in[11];
    const float* Whh = (const float*)d_in[12]; const float* bhh = (const float*)d_in[13];

    // workspace layout (92 MB total)
    char* ws = (char*)d_ws;
    u16* Acat = (u16*)(ws);                     // 32 MB  [8192][2048] = [X | H]
    u16* Brz  = (u16*)(ws + (32u << 20));       //  8 MB  [2048][2048]
    u16* Bh   = (u16*)(ws + (40u << 20));       //  4 MB  [1024][2048]
    u16* RHb  = (u16*)(ws + (44u << 20));       // 16 MB  [8192][1024] r*hidden bf16
    float* Zf = (float*)(ws + (60u << 20));     // 32 MB  z f32

    float* out_lsm = (float*)d_out;
    float* out_nh  = (float*)d_out + (size_t)B_SZ * H_SZ;

    cvt_all<<<22528, 256, 0, stream>>>(
        input, hidden, Wir, Whr, Wiz, Whz, Wih, Whh, Acat, Brz, Bh);

    // fused r+z GEMM: M=8192 N=2048 K=2048, 128x128 tiles -> 64x16 = 1024 blocks
    gemm_rz<<<1024, 256, 0, stream>>>(
        Acat, Acat + 1024, Brz, bir, bhr, biz, bhz, hidden, RHb, Zf);
    // h~ GEMM: M=8192 N=1024 K=2048 (X | RHb), 128x128 tiles -> 64x8 = 512 blocks
    gemm_h<<<512, 256, 0, stream>>>(
        Acat, RHb, Bh, bih, bhh, hidden, Zf, out_nh);

    lsm_kernel<<<B_SZ, 256, 0, stream>>>(out_nh, out_lsm);
}

// Round 10
// 327.235 us; speedup vs baseline: 1.0470x; 1.0470x over previous
//
#include <hip/hip_runtime.h>
#include <cstdint>

#define B_SZ 8192
#define IN_SZ 1024
#define H_SZ 1024

typedef unsigned short u16;
typedef __bf16 bf16_t;
typedef bf16_t bf16x8 __attribute__((ext_vector_type(8)));
typedef float floatx4 __attribute__((ext_vector_type(4)));

__device__ __forceinline__ u16 f2bf(float f) {
    unsigned int u = __float_as_uint(f);
    u += 0x7fffu + ((u >> 16) & 1u);   // RNE
    return (u16)(u >> 16);
}

__device__ __forceinline__ ushort4 cvt4(float4 v) {
    ushort4 o;
    o.x = f2bf(v.x); o.y = f2bf(v.y); o.z = f2bf(v.z); o.w = f2bf(v.w);
    return o;
}

// async global->LDS, 16B per lane; LDS dest = wave-uniform base + lane*16
__device__ __forceinline__ void g2l16(const u16* g, u16* l) {
    __builtin_amdgcn_global_load_lds(
        (__attribute__((address_space(1))) void*)(uintptr_t)g,
        (__attribute__((address_space(3))) void*)(uint32_t)(uintptr_t)l,
        16, 0, 0);
}

// phase boundary: pin order, counted vmcnt (NEVER 0 in steady state), raw barrier
template <int N>
__device__ __forceinline__ void phase_end() {
    __builtin_amdgcn_sched_barrier(0);
    if constexpr (N == 0) asm volatile("s_waitcnt vmcnt(0)" ::: "memory");
    else if constexpr (N == 4) asm volatile("s_waitcnt vmcnt(4)" ::: "memory");
    else if constexpr (N == 8) asm volatile("s_waitcnt vmcnt(8)" ::: "memory");
    __builtin_amdgcn_s_barrier();
    __builtin_amdgcn_sched_barrier(0);
}

// ---------------- fused fp32 -> bf16 conversion into K-concat layouts -----------
// Acat[8192][2048] = [bf16(input) | bf16(hidden)]
// Brz [2048][2048] = [[Wir|Whr],[Wiz|Whz]];  Bh [1024][2048] = [Wih|Whh]
__global__ __launch_bounds__(256) void cvt_all(
    const float* __restrict__ x, const float* __restrict__ h,
    const float* __restrict__ Wir, const float* __restrict__ Whr,
    const float* __restrict__ Wiz, const float* __restrict__ Whz,
    const float* __restrict__ Wih, const float* __restrict__ Whh,
    u16* __restrict__ Acat, u16* __restrict__ Brz, u16* __restrict__ Bh) {
    const int b = blockIdx.x;
    const int t = threadIdx.x;
    if (b < 8192) {
        float4 v = ((const float4*)(x + (size_t)b * 1024))[t];
        ((ushort4*)(Acat + (size_t)b * 2048))[t] = cvt4(v);
    } else if (b < 16384) {
        const int m = b - 8192;
        float4 v = ((const float4*)(h + (size_t)m * 1024))[t];
        ((ushort4*)(Acat + (size_t)m * 2048 + 1024))[t] = cvt4(v);
    } else {
        const int wb = b - 16384;   // 0..6143
        const int w = wb >> 10;
        const int n = wb & 1023;
        const float* src;
        u16* dst;
        switch (w) {
            case 0: src = Wir; dst = Brz + (size_t)n * 2048;               break;
            case 1: src = Whr; dst = Brz + (size_t)n * 2048 + 1024;        break;
            case 2: src = Wiz; dst = Brz + (size_t)(n + 1024) * 2048;      break;
            case 3: src = Whz; dst = Brz + (size_t)(n + 1024) * 2048 + 1024; break;
            case 4: src = Wih; dst = Bh + (size_t)n * 2048;                break;
            default: src = Whh; dst = Bh + (size_t)n * 2048 + 1024;        break;
        }
        float4 v = ((const float4*)(src + (size_t)n * 1024))[t];
        ((ushort4*)dst)[t] = cvt4(v);
    }
}

// ---------------- gemm_rz: r5-EXACT 256x256 ring-4 + counted vmcnt + T2 swizzle --
// Best-measured rz structure of the session (r5: 110.9us, 620 TF, 0 conflicts).
// 512 thr (8 waves, 2x4 grid, per-wave 128x64, FM=8 FN=4). Ring of 4 LDS buffers
// (buf=t&3), prefetch distance 3; per tile close: vmcnt(8)=2*LS (tile t+1
// resident, t+2/t+3 in flight, in-order queue) + raw barrier.
// r+z fused (N=2048): col<1024 -> out_rh=bf16(sigmoid(C+b)*hidden);
//                     col>=1024 -> out_zf[.,c-1024]=sigmoid(C+b)
__global__ __launch_bounds__(512) void gemm_rz(
    const u16* __restrict__ A0, const u16* __restrict__ A1,
    const u16* __restrict__ Bw,
    const float* __restrict__ bx0, const float* __restrict__ bh0,
    const float* __restrict__ bx1, const float* __restrict__ bh1,
    const float* __restrict__ hidden,
    u16* __restrict__ out_rh, float* __restrict__ out_zf) {
    constexpr int BM = 256, BN = 256, BK = 32, NKT = 64;   // K = 2048
    constexpr int PM = 128, PN = 64;                       // wave grid 2x4
    constexpr int FM = 8, FN = 4;
    constexpr int AG = 2, BG = 2, LS = AG + BG;            // 4

    __shared__ u16 As[4][BM * BK];          // 4 x 16 KB
    __shared__ u16 Bs[4][BN * BK];          // 4 x 16 KB

    const int tid = threadIdx.x;
    const int wave = tid >> 6;
    const int lane = tid & 63;
    // chunked XCD swizzle (nwg = 256)
    const int wid = blockIdx.x;
    const int swz = (wid & 7) * 32 + (wid >> 3);
    const int bn = swz & 7;
    const int bm = swz >> 3;
    const int wc = wave & 3;
    const int wr = wave >> 2;

    const floatx4 z4 = {0.f, 0.f, 0.f, 0.f};
    floatx4 acc[FM][FN];
#pragma unroll
    for (int i = 0; i < FM; ++i)
#pragma unroll
        for (int j = 0; j < FN; ++j) acc[i][j] = z4;

    // staging source coords (inverse swizzle on global address), rule #21
    int rowA[AG], gkA[AG], rowB[BG], gkB[BG];
#pragma unroll
    for (int j = 0; j < 2; ++j) {
        const int c = j * 512 + tid;
        const int sup = c >> 3;
        const int u = (c & 7) ^ (sup & 7);
        rowA[j] = sup * 2 + (u >> 2);  gkA[j] = (u & 3) * 8;
        rowB[j] = rowA[j];             gkB[j] = gkA[j];
    }

    // swizzled ds_read bases (u16 idx): frag i at base + i*512
    const int mr = lane & 15;
    const int sg = lane >> 4;               // k-slot 0..3
    const int R0 = wr * PM + mr;
    const int baseA = (R0 >> 1) * 64 + (((((R0 & 1) << 2) | sg) ^ ((R0 >> 1) & 7)) << 3);
    const int C0 = wc * PN + mr;
    const int baseB = (C0 >> 1) * 64 + (((((C0 & 1) << 2) | sg) ^ ((C0 >> 1) & 7)) << 3);

    auto stage = [&](int t) {
        const int buf = t & 3;
        const bool seg = t >= NKT / 2;
        const u16* __restrict__ Ab = seg ? A1 : A0;
        const int ka = (t & (NKT / 2 - 1)) * BK;
        const int kb = t * BK;
        u16* Asb = &As[buf][0];
        u16* Bsb = &Bs[buf][0];
#pragma unroll
        for (int j = 0; j < AG; ++j)
            g2l16(Ab + (size_t)(bm * BM + rowA[j]) * 2048 + ka + gkA[j],
                  Asb + (j * 512 + wave * 64) * 8);
#pragma unroll
        for (int j = 0; j < BG; ++j)
            g2l16(Bw + (size_t)(bn * BN + rowB[j]) * 2048 + kb + gkB[j],
                  Bsb + (j * 512 + wave * 64) * 8);
    };

    auto compute = [&](int t) {
        const u16* Asb = &As[t & 3][0];
        const u16* Bsb = &Bs[t & 3][0];
        bf16x8 af[FM], bv[FN];
#pragma unroll
        for (int i = 0; i < FM; ++i)
            af[i] = *(const bf16x8*)&Asb[baseA + i * 512];
#pragma unroll
        for (int j = 0; j < FN; ++j)
            bv[j] = *(const bf16x8*)&Bsb[baseB + j * 512];
        __builtin_amdgcn_s_setprio(1);
#pragma unroll
        for (int i = 0; i < FM; ++i)
#pragma unroll
            for (int j = 0; j < FN; ++j)
                acc[i][j] = __builtin_amdgcn_mfma_f32_16x16x32_bf16(
                    af[i], bv[j], acc[i][j], 0, 0, 0);
        __builtin_amdgcn_s_setprio(0);
    };

    // prologue: 3 tiles in flight
    stage(0); stage(1); stage(2);
    phase_end<2 * LS>();                 // S(0) resident
#pragma unroll 4
    for (int t = 0; t < NKT - 3; ++t) {  // t = 0..60
        stage(t + 3);
        compute(t);
        phase_end<2 * LS>();             // S(t+1) resident; t+2,t+3 in flight
    }
    compute(NKT - 3); phase_end<LS>();   // S(62) resident
    compute(NKT - 2); phase_end<0>();    // S(63) resident
    compute(NKT - 1);

    // epilogue: C/D layout col=lane&15, row=(lane>>4)*4+reg (m89/m91 verified)
    const int colBase = bn * BN + wc * PN + (lane & 15);
    const int rowBase = bm * BM + wr * PM + (lane >> 4) * 4;
    const bool is_r = (colBase < H_SZ);   // block-uniform (1024 % 256 == 0)
#pragma unroll
    for (int j = 0; j < FN; ++j) {
        const int coln = colBase + j * 16;
        const int cb = is_r ? coln : coln - H_SZ;
        const float bias = is_r ? (bx0[cb] + bh0[cb]) : (bx1[cb] + bh1[cb]);
#pragma unroll
        for (int i = 0; i < FM; ++i) {
#pragma unroll
            for (int r = 0; r < 4; ++r) {
                const int rown = rowBase + i * 16 + r;
                const size_t idx = (size_t)rown * H_SZ + cb;
                const float v = acc[i][j][r] + bias;
                const float s = 1.0f / (1.0f + __expf(-v));
                if (is_r) out_rh[idx] = f2bf(s * hidden[idx]);
                else      out_zf[idx] = s;
            }
        }
    }
}

// ---------------- gemm_h: r9-style 128x128 ring-3, (256,3), 512 blocks ----------
// h~ GEMM (N=1024, K=2048 = [X | r*h]): ht=tanh(C+b); out = z*h + (1-z)*ht.
// 2 blocks/CU regime — the session's best per-byte staging rate for small-work
// GEMMs (r9: ~8.5 TB/s effective).
__global__ __launch_bounds__(256, 3) void gemm_h(
    const u16* __restrict__ A0, const u16* __restrict__ A1,
    const u16* __restrict__ Bw,
    const float* __restrict__ bx0, const float* __restrict__ bh0,
    const float* __restrict__ hidden, const float* __restrict__ zbuf,
    float* __restrict__ out_f) {
    constexpr int BM = 128, BN = 128, BK = 32, NKT = 64;   // K = 2048
    constexpr int FM = 4, FN = 4, LS = 4, LNBN = 3;
    constexpr int SA0 = 2048, SA1 = 1024;

    __shared__ u16 As[3][BM * BK];         // 3 x 8 KB
    __shared__ u16 Bs[3][BN * BK];         // 3 x 8 KB

    const int tid = threadIdx.x;
    const int wave = tid >> 6;
    const int lane = tid & 63;
    const int nwg = gridDim.x;
    const int wid = blockIdx.x;
    const int swz = (wid & 7) * (nwg >> 3) + (wid >> 3);
    const int bn = swz & ((1 << LNBN) - 1);
    const int bm = swz >> LNBN;
    const int wr = wave >> 1, wc = wave & 1;   // 2x2 wave grid

    const floatx4 z4 = {0.f, 0.f, 0.f, 0.f};
    floatx4 acc[FM][FN];
#pragma unroll
    for (int i = 0; i < FM; ++i)
#pragma unroll
        for (int j = 0; j < FN; ++j) acc[i][j] = z4;

    int row[2], gk[2];
#pragma unroll
    for (int j = 0; j < 2; ++j) {
        const int c = j * 256 + tid;       // chunk 0..511
        const int sup = c >> 3;
        const int u = (c & 7) ^ (sup & 7);
        row[j] = sup * 2 + (u >> 2);
        gk[j] = (u & 3) * 8;
    }

    const int mr = lane & 15;
    const int sg = lane >> 4;
    const int R0 = wr * 64 + mr;
    const int baseA = (R0 >> 1) * 64 + (((((R0 & 1) << 2) | sg) ^ ((R0 >> 1) & 7)) << 3);
    const int C0 = wc * 64 + mr;
    const int baseB = (C0 >> 1) * 64 + (((((C0 & 1) << 2) | sg) ^ ((C0 >> 1) & 7)) << 3);

    auto stage = [&](int buf, int t) {
        const bool seg = t >= NKT / 2;
        const u16* __restrict__ Ab = seg ? A1 : A0;
        const int sA = seg ? SA1 : SA0;
        const int ka = (t & (NKT / 2 - 1)) * BK;
        const int kb = t * BK;
        u16* Asb = &As[buf][0];
        u16* Bsb = &Bs[buf][0];
#pragma unroll
        for (int j = 0; j < 2; ++j)
            g2l16(Ab + (size_t)(bm * BM + row[j]) * sA + ka + gk[j],
                  Asb + (j * 256 + wave * 64) * 8);
#pragma unroll
        for (int j = 0; j < 2; ++j)
            g2l16(Bw + (size_t)(bn * BN + row[j]) * 2048 + kb + gk[j],
                  Bsb + (j * 256 + wave * 64) * 8);
    };

    auto compute = [&](int buf) {
        const u16* Asb = &As[buf][0];
        const u16* Bsb = &Bs[buf][0];
        bf16x8 af[FM], bv[FN];
#pragma unroll
        for (int i = 0; i < FM; ++i)
            af[i] = *(const bf16x8*)&Asb[baseA + i * 512];
#pragma unroll
        for (int j = 0; j < FN; ++j)
            bv[j] = *(const bf16x8*)&Bsb[baseB + j * 512];
        __builtin_amdgcn_s_setprio(1);
#pragma unroll
        for (int i = 0; i < FM; ++i)
#pragma unroll
            for (int j = 0; j < FN; ++j)
                acc[i][j] = __builtin_amdgcn_mfma_f32_16x16x32_bf16(
                    af[i], bv[j], acc[i][j], 0, 0, 0);
        __builtin_amdgcn_s_setprio(0);
    };

    auto step = [&](int t, int bS, int bC) {
        stage(bS, t + 2);
        compute(bC);
        phase_end<LS>();
    };

    stage(0, 0); stage(1, 1);
    phase_end<LS>();
    for (int t = 0; t < 60; t += 3) {
        step(t, 2, 0); step(t + 1, 0, 1); step(t + 2, 1, 2);
    }
    step(60, 2, 0); step(61, 0, 1);
    compute(2);
    phase_end<0>();
    compute(0);

    const int colBase = bn * BN + wc * 64 + (lane & 15);
    const int rowBase = bm * BM + wr * 64 + (lane >> 4) * 4;
#pragma unroll
    for (int j = 0; j < FN; ++j) {
        const int coln = colBase + j * 16;
        const float bias = bx0[coln] + bh0[coln];
#pragma unroll
        for (int i = 0; i < FM; ++i) {
#pragma unroll
            for (int r = 0; r < 4; ++r) {
                const int rown = rowBase + i * 16 + r;
                const size_t idx = (size_t)rown * H_SZ + coln;
                const float v = acc[i][j][r] + bias;
                const float ht = tanhf(v);
                const float zz = zbuf[idx];
                const float hh = hidden[idx];
                out_f[idx] = zz * hh + (1.0f - zz) * ht;
            }
        }
    }
}

// ---------------- row-wise log_softmax over H=1024 ----------------
__global__ __launch_bounds__(256) void lsm_kernel(const float* __restrict__ nh,
                                                  float* __restrict__ out) {
    const int row = blockIdx.x;
    const int tid = threadIdx.x;
    const int wave = tid >> 6, lane = tid & 63;
    const float4 v = ((const float4*)(nh + (size_t)row * H_SZ))[tid];
    __shared__ float redm[4];
    __shared__ float reds[4];
    float m = fmaxf(fmaxf(v.x, v.y), fmaxf(v.z, v.w));
#pragma unroll
    for (int o = 32; o; o >>= 1) m = fmaxf(m, __shfl_xor(m, o));
    if (lane == 0) redm[wave] = m;
    __syncthreads();
    const float M = fmaxf(fmaxf(redm[0], redm[1]), fmaxf(redm[2], redm[3]));
    float s = __expf(v.x - M) + __expf(v.y - M) + __expf(v.z - M) + __expf(v.w - M);
#pragma unroll
    for (int o = 32; o; o >>= 1) s += __shfl_xor(s, o);
    if (lane == 0) reds[wave] = s;
    __syncthreads();
    const float S = reds[0] + reds[1] + reds[2] + reds[3];
    const float lse = M + __logf(S);
    float4 ov;
    ov.x = v.x - lse; ov.y = v.y - lse; ov.z = v.z - lse; ov.w = v.w - lse;
    ((float4*)(out + (size_t)row * H_SZ))[tid] = ov;
}

extern "C" void kernel_launch(void* const* d_in, const int* in_sizes, int n_in,
                              void* d_out, int out_size, void* d_ws, size_t ws_size,
                              hipStream_t stream) {
    const float* input  = (const float*)d_in[0];
    const float* hidden = (const float*)d_in[1];
    const float* Wir = (const float*)d_in[2];  const float* bir = (const float*)d_in[3];
    const float* Whr = (const float*)d_in[4];  const float* bhr = (const float*)d_in[5];
    const float* Wiz = (const float*)d_in[6];  const float* biz = (const float*)d_in[7];
    const float* Whz = (const float*)d_in[8];  const float* bhz = (const float*)d_in[9];
    const float* Wih = (const float*)d_in[10]; const float* bih = (const float*)d_in[11];
    const float* Whh = (const float*)d_in[12]; const float* bhh = (const float*)d_in[13];

    // workspace layout (92 MB total)
    char* ws = (char*)d_ws;
    u16* Acat = (u16*)(ws);                     // 32 MB  [8192][2048] = [X | H]
    u16* Brz  = (u16*)(ws + (32u << 20));       //  8 MB  [2048][2048]
    u16* Bh   = (u16*)(ws + (40u << 20));       //  4 MB  [1024][2048]
    u16* RHb  = (u16*)(ws + (44u << 20));       // 16 MB  [8192][1024] r*hidden bf16
    float* Zf = (float*)(ws + (60u << 20));     // 32 MB  z f32

    float* out_lsm = (float*)d_out;
    float* out_nh  = (float*)d_out + (size_t)B_SZ * H_SZ;

    cvt_all<<<22528, 256, 0, stream>>>(
        input, hidden, Wir, Whr, Wiz, Whz, Wih, Whh, Acat, Brz, Bh);

    // fused r+z GEMM: M=8192 N=2048 K=2048, 256x256 tiles -> 256 blocks (r5-exact)
    gemm_rz<<<256, 512, 0, stream>>>(
        Acat, Acat + 1024, Brz, bir, bhr, biz, bhz, hidden, RHb, Zf);
    // h~ GEMM: M=8192 N=1024 K=2048 (X | RHb), 128x128 tiles -> 512 blocks (r9-style)
    gemm_h<<<512, 256, 0, stream>>>(
        Acat, RHb, Bh, bih, bhh, hidden, Zf, out_nh);

    lsm_kernel<<<B_SZ, 256, 0, stream>>>(out_nh, out_lsm);
}